// Round 1
// baseline (503.640 us; speedup 1.0000x reference)
//
#include <hip/hip_runtime.h>
#include <math.h>

#define D 128

// --- Pass 1: segment start offsets from the sorted index array ---------------
// starts[j] = first row whose index >= j, for j in [0, B]; starts[B] = N.
__global__ __launch_bounds__(256) void seg_starts_kernel(
    const int* __restrict__ index, int* __restrict__ starts, int N, int B)
{
    int i = blockIdx.x * blockDim.x + threadIdx.x;
    if (i >= N) return;
    int cur  = index[i];
    int prev = (i == 0) ? -1 : index[i - 1];
    for (int j = prev + 1; j <= cur; ++j) starts[j] = i;
    if (i == N - 1) {
        for (int j = cur + 1; j <= B; ++j) starts[j] = N;
    }
}

// e = exp(tanh(v)); tanh(v) = 1 - 2/(1+exp(2v)). Correct limits at +/-inf.
__device__ __forceinline__ float fast_exp_tanh(float v) {
    float e2 = __expf(2.0f * v);
    float th = 1.0f - 2.0f * __builtin_amdgcn_rcpf(1.0f + e2);
    return __expf(th);
}

// One softmax/accumulate step for one (possibly clamped) row.
// r is the UNclamped row id; e is zeroed when r >= end.
__device__ __forceinline__ void seg_step(
    const float4& xv, const float4& rv, int r, int end,
    const float4& wx, const float4& wr, float bias,
    float4& acc, float& sum_e)
{
    float partial = xv.x*wx.x + xv.y*wx.y + xv.z*wx.z + xv.w*wx.w
                  + rv.x*wr.x + rv.y*wr.y + rv.z*wr.z + rv.w*wr.w;
    #pragma unroll
    for (int off = 16; off >= 1; off >>= 1)
        partial += __shfl_xor(partial, off);   // reduce within 32-lane half
    float e = fast_exp_tanh(partial + bias);
    e = (r < end) ? e : 0.f;
    acc.x += e * xv.x; acc.y += e * xv.y;
    acc.z += e * xv.z; acc.w += e * xv.w;
    sum_e += e;
}

// --- Pass 2: fused logit + segment softmax + weighted segment sum ------------
// ONE WAVE per segment (4 segments per 256-thread block). Half-wave scheme:
// lanes 0-31 handle row r, lanes 32-63 handle row r+1; lane (hl, c) loads the
// float4 of dims 4c..4c+3, so the wave reads 1 KB contiguous per array per
// iteration. Software-pipelined with PREFETCH DEPTH 2 (4 float4 loads in
// flight per wave) to cover HBM latency; avg segment = ~30 rows = ~15 iters
// per wave, so startup latency is amortized ~4x better than the old
// 4-waves-per-segment scheme, and there is no LDS combine / __syncthreads.
// src = tanh(.) in [-1,1] so exp never overflows; segment-max subtraction is
// a numerical no-op and is dropped.
__global__ __launch_bounds__(256) void attn_seg_kernel(
    const float* __restrict__ x,
    const float* __restrict__ ref,
    const int*   __restrict__ starts,
    const float* __restrict__ W,
    const float* __restrict__ b,
    float*       __restrict__ out,
    int B)
{
    const int wave = threadIdx.x >> 6;                 // 0..3
    const int seg  = blockIdx.x * 4 + wave;
    if (seg >= B) return;
    const int lane = threadIdx.x & 63;
    const int hl   = lane >> 5;   // which row of the pair
    const int c    = lane & 31;   // column group: dims 4c..4c+3

    const int start = starts[seg];
    const int end   = starts[seg + 1];
    const int cnt   = end - start;

    const float4 wx = ((const float4*)W)[c];        // W[0:128] frag
    const float4 wr = ((const float4*)(W + D))[c];  // W[128:256] frag
    const float bias = b[0];

    float4 acc   = make_float4(0.f, 0.f, 0.f, 0.f);
    float  sum_e = 0.f;

    if (cnt > 0) {
        const int last  = end - 1;        // clamp target (valid since cnt>0)
        const int niter = (cnt + 1) >> 1; // 2 rows per iteration per wave

        // Pipeline slots a (iter t) and b (iter t+1)
        int r0 = start + hl;
        int p0 = min(r0, last);
        float4 xa = ((const float4*)(x   + (size_t)p0 * D))[c];
        float4 fa = ((const float4*)(ref + (size_t)p0 * D))[c];
        int r1 = r0 + 2;
        int p1 = min(r1, last);
        float4 xb = ((const float4*)(x   + (size_t)p1 * D))[c];
        float4 fb = ((const float4*)(ref + (size_t)p1 * D))[c];

        int t = 0;
        for (; t + 2 < niter; t += 2) {
            // prefetch iters t+2, t+3 before consuming t, t+1
            const int r2 = r0 + 4; const int p2 = min(r2, last);
            float4 xc = ((const float4*)(x   + (size_t)p2 * D))[c];
            float4 fc = ((const float4*)(ref + (size_t)p2 * D))[c];
            const int r3 = r1 + 4; const int p3 = min(r3, last);
            float4 xd = ((const float4*)(x   + (size_t)p3 * D))[c];
            float4 fd = ((const float4*)(ref + (size_t)p3 * D))[c];

            seg_step(xa, fa, r0, end, wx, wr, bias, acc, sum_e);
            seg_step(xb, fb, r1, end, wx, wr, bias, acc, sum_e);

            xa = xc; fa = fc; r0 = r2;
            xb = xd; fb = fd; r1 = r3;
        }
        // Remaining 1 or 2 iterations already loaded in slots a/b.
        seg_step(xa, fa, r0, end, wx, wr, bias, acc, sum_e);
        if (t + 1 < niter)
            seg_step(xb, fb, r1, end, wx, wr, bias, acc, sum_e);
    }

    // Combine the two half-wave accumulators in-register (lanes i <-> i+32
    // hold the same dims 4c..4c+3 for alternating rows).
    acc.x += __shfl_xor(acc.x, 32);
    acc.y += __shfl_xor(acc.y, 32);
    acc.z += __shfl_xor(acc.z, 32);
    acc.w += __shfl_xor(acc.w, 32);
    sum_e += __shfl_xor(sum_e, 32);

    if (hl == 0) {
        const float inv = 1.0f / (sum_e + 1e-16f);
        float4 o;
        o.x = acc.x * inv; o.y = acc.y * inv;
        o.z = acc.z * inv; o.w = acc.w * inv;
        ((float4*)(out + (size_t)seg * D))[c] = o;   // 512 B per wave
    }
}

extern "C" void kernel_launch(void* const* d_in, const int* in_sizes, int n_in,
                              void* d_out, int out_size, void* d_ws, size_t ws_size,
                              hipStream_t stream) {
    const float* x     = (const float*)d_in[0];
    const float* ref   = (const float*)d_in[1];
    const int*   index = (const int*)d_in[2];
    // d_in[3] = batch_size (device scalar; B derived from out_size instead)
    const float* W     = (const float*)d_in[4];
    const float* b     = (const float*)d_in[5];
    float* out = (float*)d_out;

    const int N = in_sizes[0] / D;
    const int B = out_size / D;

    int* starts = (int*)d_ws;  // B+1 ints

    seg_starts_kernel<<<(N + 255) / 256, 256, 0, stream>>>(index, starts, N, B);
    attn_seg_kernel<<<(B + 3) / 4, 256, 0, stream>>>(x, ref, starts, W, b, out, B);
}

// Round 3
// 493.784 us; speedup vs baseline: 1.0200x; 1.0200x over previous
//
#include <hip/hip_runtime.h>
#include <math.h>

#define D 128

typedef float floatx4 __attribute__((ext_vector_type(4)));

// --- Pass 1: segment start offsets from the sorted index array ---------------
// starts[j] = first row whose index >= j, for j in [0, B]; starts[B] = N.
__global__ __launch_bounds__(256) void seg_starts_kernel(
    const int* __restrict__ index, int* __restrict__ starts, int N, int B)
{
    int i = blockIdx.x * blockDim.x + threadIdx.x;
    if (i >= N) return;
    int cur  = index[i];
    int prev = (i == 0) ? -1 : index[i - 1];
    for (int j = prev + 1; j <= cur; ++j) starts[j] = i;
    if (i == N - 1) {
        for (int j = cur + 1; j <= B; ++j) starts[j] = N;
    }
}

// e = exp(tanh(v)); tanh(v) = 1 - 2/(1+exp(2v)). Correct limits at +/-inf.
__device__ __forceinline__ float fast_exp_tanh(float v) {
    float e2 = __expf(2.0f * v);
    float th = 1.0f - 2.0f * __builtin_amdgcn_rcpf(1.0f + e2);
    return __expf(th);
}

// --- Pass 2: fused logit + segment softmax + weighted segment sum ------------
// ONE WAVE per segment (4 segments per 256-thread block), half-wave scheme:
// lanes 0-31 handle row r, lanes 32-63 row r+1; lane (hl,c) holds dims 4c..4c+3.
//
// Read-path tuning (round-2 theory): both prior structures pinned at the same
// 3.24 TB/s combined read rate (1.67 TB/s HBM + 1.67 TB/s L3, FETCH == exactly
// L3 capacity) -> suspected L3 install-path limit on read-allocate. Fix:
//  - ref is loaded NON-TEMPORALLY (no L3 allocate): halves install traffic and
//    leaves the whole 256 MB x array L3-resident across dispatches.
//  - x stays cacheable (L3-served in steady state).
//  - prefetch depth 4 (8 float4 loads in flight per wave).
__global__ __launch_bounds__(256) void attn_seg_kernel(
    const float* __restrict__ x,
    const float* __restrict__ ref,
    const int*   __restrict__ starts,
    const float* __restrict__ W,
    const float* __restrict__ b,
    float*       __restrict__ out,
    int B)
{
    const int wave = threadIdx.x >> 6;                 // 0..3
    const int seg  = blockIdx.x * 4 + wave;
    if (seg >= B) return;
    const int lane = threadIdx.x & 63;
    const int hl   = lane >> 5;   // which row of the pair
    const int c    = lane & 31;   // column group: dims 4c..4c+3

    const int start = starts[seg];
    const int end   = starts[seg + 1];
    const int cnt   = end - start;

    const float4 wx = ((const float4*)W)[c];        // W[0:128] frag
    const float4 wr = ((const float4*)(W + D))[c];  // W[128:256] frag
    const float bias = b[0];

    float4 acc   = make_float4(0.f, 0.f, 0.f, 0.f);
    float  sum_e = 0.f;

    if (cnt > 0) {
        const int last  = end - 1;        // clamp target (valid since cnt>0)
        const int niter = (cnt + 1) >> 1; // 2 rows per iteration per wave
        const int ntrip = (niter + 3) >> 2;
        const int rb    = start + hl;

        // x: normal (cacheable, L3-resident in steady state)
        // ref: non-temporal (stream from HBM, no cache install)
#define SLOAD(XV, RV, R) do { const int p_ = min((R), last);                        \
        XV = *(const float4*)(x + (size_t)p_ * D + 4*c);                            \
        floatx4 rv_ = __builtin_nontemporal_load(                                   \
            (const floatx4*)(ref + (size_t)p_ * D + 4*c));                          \
        RV = make_float4(rv_.x, rv_.y, rv_.z, rv_.w);                               \
    } while (0)

#define SSTEP(XV, RV, R) do {                                                      \
        float p_ = XV.x*wx.x + XV.y*wx.y + XV.z*wx.z + XV.w*wx.w                   \
                 + RV.x*wr.x + RV.y*wr.y + RV.z*wr.z + RV.w*wr.w;                  \
        p_ += __shfl_xor(p_, 16); p_ += __shfl_xor(p_, 8);                         \
        p_ += __shfl_xor(p_, 4);  p_ += __shfl_xor(p_, 2);                         \
        p_ += __shfl_xor(p_, 1);                       /* reduce within half */    \
        float e_ = fast_exp_tanh(p_ + bias);                                       \
        e_ = ((R) < end) ? e_ : 0.f;                                               \
        acc.x += e_*XV.x; acc.y += e_*XV.y; acc.z += e_*XV.z; acc.w += e_*XV.w;    \
        sum_e += e_;                                                               \
    } while (0)

        // Pipeline: 4 slots (iters t..t+3), 8 rows in flight.
        int r0 = rb, r1 = rb + 2, r2 = rb + 4, r3 = rb + 6;
        float4 xa,fa, xb,fb, xc,fc, xd,fd;
        SLOAD(xa,fa,r0); SLOAD(xb,fb,r1); SLOAD(xc,fc,r2); SLOAD(xd,fd,r3);

        for (int tr = 0; tr < ntrip - 1; ++tr) {
            const int n0 = r0 + 8, n1 = r1 + 8, n2 = r2 + 8, n3 = r3 + 8;
            float4 ya,ga, yb,gb, yc,gc, yd,gd;
            SLOAD(ya,ga,n0); SLOAD(yb,gb,n1); SLOAD(yc,gc,n2); SLOAD(yd,gd,n3);

            SSTEP(xa,fa,r0); SSTEP(xb,fb,r1); SSTEP(xc,fc,r2); SSTEP(xd,fd,r3);

            xa=ya; fa=ga; r0=n0;  xb=yb; fb=gb; r1=n1;
            xc=yc; fc=gc; r2=n2;  xd=yd; fd=gd; r3=n3;
        }
        // Final trip: slots already loaded; rows >= end are predicated to e=0.
        SSTEP(xa,fa,r0); SSTEP(xb,fb,r1); SSTEP(xc,fc,r2); SSTEP(xd,fd,r3);

#undef SLOAD
#undef SSTEP
    }

    // Combine the two half-wave accumulators in-register.
    acc.x += __shfl_xor(acc.x, 32);
    acc.y += __shfl_xor(acc.y, 32);
    acc.z += __shfl_xor(acc.z, 32);
    acc.w += __shfl_xor(acc.w, 32);
    sum_e += __shfl_xor(sum_e, 32);

    if (hl == 0) {
        const float inv = 1.0f / (sum_e + 1e-16f);
        float4 o = make_float4(acc.x*inv, acc.y*inv, acc.z*inv, acc.w*inv);
        *(float4*)(out + (size_t)seg * D + 4*c) = o;   // 512 B per wave
    }
}

extern "C" void kernel_launch(void* const* d_in, const int* in_sizes, int n_in,
                              void* d_out, int out_size, void* d_ws, size_t ws_size,
                              hipStream_t stream) {
    const float* x     = (const float*)d_in[0];
    const float* ref   = (const float*)d_in[1];
    const int*   index = (const int*)d_in[2];
    // d_in[3] = batch_size (device scalar; B derived from out_size instead)
    const float* W     = (const float*)d_in[4];
    const float* b     = (const float*)d_in[5];
    float* out = (float*)d_out;

    const int N = in_sizes[0] / D;
    const int B = out_size / D;

    int* starts = (int*)d_ws;  // B+1 ints

    seg_starts_kernel<<<(N + 255) / 256, 256, 0, stream>>>(index, starts, N, B);
    attn_seg_kernel<<<(B + 3) / 4, 256, 0, stream>>>(x, ref, starts, W, b, out, B);
}